// Round 2
// baseline (179.059 us; speedup 1.0000x reference)
//
#include <hip/hip_runtime.h>
#include <math.h>

// B=65536, D=8, H=2 (hd=4), S=15 tokens, A=20 outputs.
// 8 lanes per element, 2 tokens per lane (token 15 is a computed-but-ignored pad),
// 32 elements per 256-thread block, grid = 65536/32 = 2048 blocks.
// Fused no-max softmax: scores are bounded (|0.5*q.k| << 127/log2e), so
// exp2((0.5*log2e*q).k) accumulated in a single pass over keys.
#define EPB 32
#define ESTRIDE 132   // 16 tokens * 8 floats + 4 pad -> element bank-quad offsets 0..7
#define BTOT 65536
#define C_SCALE 0.72134752044f  // 0.5 * log2(e)

__device__ __forceinline__ float exp2_fast(float x) {
#if defined(__has_builtin)
#if __has_builtin(__builtin_amdgcn_exp2f)
  return __builtin_amdgcn_exp2f(x);
#else
  return exp2f(x);
#endif
#else
  return exp2f(x);
#endif
}

__device__ __forceinline__ void attn_layer(
    float x[2][8], float* kb, float* vb, int g,
    const float* __restrict__ Wqkv, const float* __restrict__ bqkv,
    const float* __restrict__ Wo, const float* __restrict__ bo,
    const float* __restrict__ Wl, const float* __restrict__ bl)
{
  float q[2][8];
#pragma unroll
  for (int i = 0; i < 2; ++i) {
    const int t = 2 * g + i;
    float k[8], v[8];
#pragma unroll
    for (int c = 0; c < 8; ++c) {
      float aq = bqkv[c];
      float ak = bqkv[8 + c];
      float av = bqkv[16 + c];
#pragma unroll
      for (int j = 0; j < 8; ++j) {
        aq = fmaf(x[i][j], Wqkv[c * 8 + j], aq);
        ak = fmaf(x[i][j], Wqkv[(8 + c) * 8 + j], ak);
        av = fmaf(x[i][j], Wqkv[(16 + c) * 8 + j], av);
      }
      q[i][c] = aq * C_SCALE;  // fold softmax scale + log2e into q
      k[c] = ak; v[c] = av;
    }
    float4* kd = (float4*)(kb + t * 8);
    kd[0] = make_float4(k[0], k[1], k[2], k[3]);
    kd[1] = make_float4(k[4], k[5], k[6], k[7]);
    float4* vd = (float4*)(vb + t * 8);
    vd[0] = make_float4(v[0], v[1], v[2], v[3]);
    vd[1] = make_float4(v[4], v[5], v[6], v[7]);
  }
  __syncthreads();
  float o[2][8] = {{0.f,0.f,0.f,0.f,0.f,0.f,0.f,0.f},
                   {0.f,0.f,0.f,0.f,0.f,0.f,0.f,0.f}};
  float sum00 = 0.f, sum01 = 0.f, sum10 = 0.f, sum11 = 0.f;
#pragma unroll
  for (int u = 0; u < 15; ++u) {
    const float4 k0 = *(const float4*)(kb + u * 8);
    const float4 k1 = *(const float4*)(kb + u * 8 + 4);
    const float4 v0 = *(const float4*)(vb + u * 8);
    const float4 v1 = *(const float4*)(vb + u * 8 + 4);
#pragma unroll
    for (int i = 0; i < 2; ++i) {
      float s0 = q[i][0] * k0.x;
      s0 = fmaf(q[i][1], k0.y, s0); s0 = fmaf(q[i][2], k0.z, s0); s0 = fmaf(q[i][3], k0.w, s0);
      float s1 = q[i][4] * k1.x;
      s1 = fmaf(q[i][5], k1.y, s1); s1 = fmaf(q[i][6], k1.z, s1); s1 = fmaf(q[i][7], k1.w, s1);
      const float e0 = exp2_fast(s0);
      const float e1 = exp2_fast(s1);
      if (i == 0) { sum00 += e0; sum01 += e1; } else { sum10 += e0; sum11 += e1; }
      o[i][0] = fmaf(e0, v0.x, o[i][0]); o[i][1] = fmaf(e0, v0.y, o[i][1]);
      o[i][2] = fmaf(e0, v0.z, o[i][2]); o[i][3] = fmaf(e0, v0.w, o[i][3]);
      o[i][4] = fmaf(e1, v1.x, o[i][4]); o[i][5] = fmaf(e1, v1.y, o[i][5]);
      o[i][6] = fmaf(e1, v1.z, o[i][6]); o[i][7] = fmaf(e1, v1.w, o[i][7]);
    }
  }
#pragma unroll
  for (int i = 0; i < 2; ++i) {
    const float r0 = 1.0f / (i == 0 ? sum00 : sum10);
    const float r1 = 1.0f / (i == 0 ? sum01 : sum11);
#pragma unroll
    for (int d = 0; d < 4; ++d) { o[i][d] *= r0; o[i][4 + d] *= r1; }
    float xn[8];
#pragma unroll
    for (int c = 0; c < 8; ++c) {
      float acc = bo[c];
#pragma unroll
      for (int j = 0; j < 8; ++j) acc = fmaf(o[i][j], Wo[c * 8 + j], acc);
      xn[c] = x[i][c] + acc;
    }
#pragma unroll
    for (int c = 0; c < 8; ++c) {
      float acc = bl[c];
#pragma unroll
      for (int j = 0; j < 8; ++j) acc = fmaf(xn[j], Wl[c * 8 + j], acc);
      x[i][c] = xn[c] + fmaxf(acc, 0.0f);
    }
  }
  __syncthreads();  // protect kb/vb before next layer's writes
}

__global__ __launch_bounds__(256) void BetterBot_44169443672375_kernel(
    const int* __restrict__ dice_type, const int* __restrict__ dice_star,
    const int* __restrict__ summon_lvl,
    const float* __restrict__ emb_dice, const float* __restrict__ emb_star,
    const float* __restrict__ emb_btns,
    const float* __restrict__ Wout, const float* __restrict__ bout,
    const float* __restrict__ Wqkv0, const float* __restrict__ bqkv0,
    const float* __restrict__ Wo0, const float* __restrict__ bo0,
    const float* __restrict__ Wl0, const float* __restrict__ bl0,
    const float* __restrict__ Wqkv1, const float* __restrict__ bqkv1,
    const float* __restrict__ Wo1, const float* __restrict__ bo1,
    const float* __restrict__ Wl1, const float* __restrict__ bl1,
    float* __restrict__ out)
{
  __shared__ __align__(16) float kb_s[EPB * ESTRIDE];
  __shared__ __align__(16) float vb_s[EPB * ESTRIDE];
  const int tid = threadIdx.x;
  const int e = tid >> 3;      // element within block (0..31)
  const int g = tid & 7;       // lane within element group
  const int ge = blockIdx.x * EPB + e;
  float* kb = kb_s + e * ESTRIDE;
  float* vb = vb_s + e * ESTRIDE;

  float x[2][8];
#pragma unroll
  for (int i = 0; i < 2; ++i) {
    const int t = 2 * g + i;
    if (t < 15) {
      const float* row;
      if (t < 5)       row = emb_dice + 8 * dice_type[ge * 5 + t];
      else if (t < 10) row = emb_star + 8 * dice_star[ge * 5 + (t - 5)];
      else             row = emb_btns + 8 * summon_lvl[ge * 5 + (t - 10)];
      const float4 r0 = ((const float4*)row)[0];
      const float4 r1 = ((const float4*)row)[1];
      x[i][0] = r0.x; x[i][1] = r0.y; x[i][2] = r0.z; x[i][3] = r0.w;
      x[i][4] = r1.x; x[i][5] = r1.y; x[i][6] = r1.z; x[i][7] = r1.w;
    } else {
#pragma unroll
      for (int j = 0; j < 8; ++j) x[i][j] = 0.f;
    }
  }

  attn_layer(x, kb, vb, g, Wqkv0, bqkv0, Wo0, bo0, Wl0, bl0);
  attn_layer(x, kb, vb, g, Wqkv1, bqkv1, Wo1, bo1, Wl1, bl1);

  // epilogue: mean over 15 tokens via shfl_xor butterfly within the 8-lane group
  const bool pad = (g == 7);
  float p[8];
#pragma unroll
  for (int j = 0; j < 8; ++j) p[j] = x[0][j] + (pad ? 0.f : x[1][j]);
#pragma unroll
  for (int j = 0; j < 8; ++j) p[j] += __shfl_xor(p[j], 1);
#pragma unroll
  for (int j = 0; j < 8; ++j) p[j] += __shfl_xor(p[j], 2);
#pragma unroll
  for (int j = 0; j < 8; ++j) p[j] += __shfl_xor(p[j], 4);
  float mean[8];
#pragma unroll
  for (int j = 0; j < 8; ++j) mean[j] = p[j] * (1.0f / 15.0f);

  // head: 20 outputs per element across 8 lanes (lane g -> a = g, 8+g, 16+g<20)
  const int obase = ge * 20;
#pragma unroll
  for (int r = 0; r < 3; ++r) {
    const int a = r * 8 + g;
    if (a < 20) {
      float acc = bout[a];
#pragma unroll
      for (int j = 0; j < 8; ++j) acc = fmaf(mean[j], Wout[a * 8 + j], acc);
      out[obase + a] = acc;
    }
  }
}

extern "C" void kernel_launch(void* const* d_in, const int* in_sizes, int n_in,
                              void* d_out, int out_size, void* d_ws, size_t ws_size,
                              hipStream_t stream) {
  const int*   dice_type  = (const int*)d_in[0];
  const int*   dice_star  = (const int*)d_in[1];
  const int*   summon_lvl = (const int*)d_in[2];
  const float* emb_dice   = (const float*)d_in[3];
  const float* emb_star   = (const float*)d_in[4];
  const float* emb_btns   = (const float*)d_in[5];
  const float* Wout       = (const float*)d_in[6];
  const float* bout       = (const float*)d_in[7];
  const float* Wqkv0      = (const float*)d_in[8];
  const float* bqkv0      = (const float*)d_in[9];
  const float* Wo0        = (const float*)d_in[10];
  const float* bo0        = (const float*)d_in[11];
  const float* Wl0        = (const float*)d_in[12];
  const float* bl0        = (const float*)d_in[13];
  const float* Wqkv1      = (const float*)d_in[14];
  const float* bqkv1      = (const float*)d_in[15];
  const float* Wo1        = (const float*)d_in[16];
  const float* bo1        = (const float*)d_in[17];
  const float* Wl1        = (const float*)d_in[18];
  const float* bl1        = (const float*)d_in[19];
  float* out = (float*)d_out;

  dim3 grid(BTOT / EPB), block(256);
  hipLaunchKernelGGL(BetterBot_44169443672375_kernel, grid, block, 0, stream,
                     dice_type, dice_star, summon_lvl,
                     emb_dice, emb_star, emb_btns, Wout, bout,
                     Wqkv0, bqkv0, Wo0, bo0, Wl0, bl0,
                     Wqkv1, bqkv1, Wo1, bo1, Wl1, bl1,
                     out);
}

// Round 3
// 128.726 us; speedup vs baseline: 1.3910x; 1.3910x over previous
//
#include <hip/hip_runtime.h>
#include <math.h>

// B=65536, D=8, H=2 (hd=4), S=15 tokens, A=20 outputs.
// R3: one token per lane (16 lanes/element, lane 15 pad), 16 elements/block,
// 4096 blocks. Layer 0 is fully table-driven: only 32 distinct embedding rows
// exist, so qkv0 (32x24) and the layer-0 softmax numerators e[qi][ki][head]
// (32x32x2) are built once per block in LDS. Layer 1 uses the fused no-max
// single-pass softmax validated in R2.
#define EPB 16
#define BTOT 65536
#define C_SCALE 0.72134752044f  // 0.5 * log2(e): e = exp2(C*(q.k))
#define QSTR 28                  // qkv table row stride (floats); 112B = 16B-mult

__device__ __forceinline__ float exp2_fast(float x) {
#if defined(__has_builtin)
#if __has_builtin(__builtin_amdgcn_exp2f)
  return __builtin_amdgcn_exp2f(x);
#else
  return exp2f(x);
#endif
#else
  return exp2f(x);
#endif
}

__global__ __launch_bounds__(256) void BetterBot_44169443672375_kernel(
    const int* __restrict__ dice_type, const int* __restrict__ dice_star,
    const int* __restrict__ summon_lvl,
    const float* __restrict__ emb_dice, const float* __restrict__ emb_star,
    const float* __restrict__ emb_btns,
    const float* __restrict__ Wout, const float* __restrict__ bout,
    const float* __restrict__ Wqkv0, const float* __restrict__ bqkv0,
    const float* __restrict__ Wo0, const float* __restrict__ bo0,
    const float* __restrict__ Wl0, const float* __restrict__ bl0,
    const float* __restrict__ Wqkv1, const float* __restrict__ bqkv1,
    const float* __restrict__ Wo1, const float* __restrict__ bo1,
    const float* __restrict__ Wl1, const float* __restrict__ bl1,
    float* __restrict__ out)
{
  __shared__ __align__(16) float qkvT[32 * QSTR];   // [32][q0:8 k8:16 v16:24 pad]
  __shared__ __align__(8)  float2 eT[32 * 33];      // e[qi][ki] = (e_h0, e_h1)
  __shared__ __align__(16) float xT[32][8];         // raw embedding rows
  __shared__ int idxT[EPB][17];                     // combined idx per token
  __shared__ __align__(16) float kb[EPB][17][8];    // layer-1 k
  __shared__ __align__(16) float vb[EPB][17][8];    // layer-1 v

  const int tid = threadIdx.x;
  const int e = tid >> 4;       // element in block
  const int t = tid & 15;       // token (15 = pad lane)
  const int ge = blockIdx.x * EPB + e;

  // ---- phase 1: own combined index + qkv0/x tables (all 256 threads) ----
  int myc = 0;
  if (t < 15) {
    int c;
    if (t < 5)       c = dice_type[ge * 5 + t];
    else if (t < 10) c = 15 + dice_star[ge * 5 + (t - 5)];
    else             c = 30 + summon_lvl[ge * 5 + (t - 10)];
    idxT[e][t] = c;
    myc = c;
  }
  {
    const int c = tid >> 3;        // 0..31
    const int l8 = tid & 7;        // 8 threads per row, 3 cols each
    const float* er;
    if (c < 15)      er = emb_dice + 8 * c;
    else if (c < 30) er = emb_star + 8 * (c - 15);
    else             er = emb_btns + 8 * (c - 30);
    const float4 r0 = ((const float4*)er)[0];
    const float4 r1 = ((const float4*)er)[1];
    float r[8] = {r0.x, r0.y, r0.z, r0.w, r1.x, r1.y, r1.z, r1.w};
    xT[c][l8] = r[l8];
#pragma unroll
    for (int cc = 0; cc < 3; ++cc) {
      const int col = l8 * 3 + cc;   // 0..23, each exactly once
      float acc = bqkv0[col];
#pragma unroll
      for (int j = 0; j < 8; ++j) acc = fmaf(r[j], Wqkv0[col * 8 + j], acc);
      qkvT[c * QSTR + col] = acc;
    }
  }
  __syncthreads();

  // ---- phase 2: layer-0 exp table, 4 (qi,ki) pairs per thread ----
  {
    const int p0 = tid * 4;
    const int qi = p0 >> 5;                  // same qi for all 4 pairs
    const float* qr = qkvT + qi * QSTR;      // q row
    float qv[8];
#pragma unroll
    for (int j = 0; j < 8; ++j) qv[j] = qr[j];
#pragma unroll
    for (int jj = 0; jj < 4; ++jj) {
      const int ki = (p0 & 31) + jj;
      const float* kr = qkvT + ki * QSTR + 8;
      float s0 = qv[0] * kr[0];
      s0 = fmaf(qv[1], kr[1], s0); s0 = fmaf(qv[2], kr[2], s0); s0 = fmaf(qv[3], kr[3], s0);
      float s1 = qv[4] * kr[4];
      s1 = fmaf(qv[5], kr[5], s1); s1 = fmaf(qv[6], kr[6], s1); s1 = fmaf(qv[7], kr[7], s1);
      eT[qi * 33 + ki] = make_float2(exp2_fast(C_SCALE * s0), exp2_fast(C_SCALE * s1));
    }
  }
  __syncthreads();

  // ---- layer 0 (table-driven) + layer-1 qkv ----
  float x[8] = {0.f, 0.f, 0.f, 0.f, 0.f, 0.f, 0.f, 0.f};
  float q1[8];
  if (t < 15) {
    const float4 x0a = *(const float4*)(xT[myc]);
    const float4 x0b = *(const float4*)(xT[myc] + 4);
    x[0] = x0a.x; x[1] = x0a.y; x[2] = x0a.z; x[3] = x0a.w;
    x[4] = x0b.x; x[5] = x0b.y; x[6] = x0b.z; x[7] = x0b.w;

    float o[8] = {0.f, 0.f, 0.f, 0.f, 0.f, 0.f, 0.f, 0.f};
    float sum0 = 0.f, sum1 = 0.f;
    const float2* myE = eT + myc * 33;
#pragma unroll
    for (int u = 0; u < 15; ++u) {
      const int uc = idxT[e][u];
      const float2 ee = myE[uc];
      const float4 v0 = *(const float4*)(qkvT + uc * QSTR + 16);
      const float4 v1 = *(const float4*)(qkvT + uc * QSTR + 20);
      sum0 += ee.x; sum1 += ee.y;
      o[0] = fmaf(ee.x, v0.x, o[0]); o[1] = fmaf(ee.x, v0.y, o[1]);
      o[2] = fmaf(ee.x, v0.z, o[2]); o[3] = fmaf(ee.x, v0.w, o[3]);
      o[4] = fmaf(ee.y, v1.x, o[4]); o[5] = fmaf(ee.y, v1.y, o[5]);
      o[6] = fmaf(ee.y, v1.z, o[6]); o[7] = fmaf(ee.y, v1.w, o[7]);
    }
    const float r0 = 1.0f / sum0, r1 = 1.0f / sum1;
#pragma unroll
    for (int d = 0; d < 4; ++d) { o[d] *= r0; o[4 + d] *= r1; }
    float xn[8];
#pragma unroll
    for (int c = 0; c < 8; ++c) {
      float acc = bo0[c];
#pragma unroll
      for (int j = 0; j < 8; ++j) acc = fmaf(o[j], Wo0[c * 8 + j], acc);
      xn[c] = x[c] + acc;
    }
#pragma unroll
    for (int c = 0; c < 8; ++c) {
      float acc = bl0[c];
#pragma unroll
      for (int j = 0; j < 8; ++j) acc = fmaf(xn[j], Wl0[c * 8 + j], acc);
      x[c] = xn[c] + fmaxf(acc, 0.0f);
    }

    // layer-1 qkv for own token
    float k1[8], v1[8];
#pragma unroll
    for (int c = 0; c < 8; ++c) {
      float aq = bqkv1[c];
      float ak = bqkv1[8 + c];
      float av = bqkv1[16 + c];
#pragma unroll
      for (int j = 0; j < 8; ++j) {
        aq = fmaf(x[j], Wqkv1[c * 8 + j], aq);
        ak = fmaf(x[j], Wqkv1[(8 + c) * 8 + j], ak);
        av = fmaf(x[j], Wqkv1[(16 + c) * 8 + j], av);
      }
      q1[c] = aq * C_SCALE;
      k1[c] = ak; v1[c] = av;
    }
    float4* kd = (float4*)kb[e][t];
    kd[0] = make_float4(k1[0], k1[1], k1[2], k1[3]);
    kd[1] = make_float4(k1[4], k1[5], k1[6], k1[7]);
    float4* vd = (float4*)vb[e][t];
    vd[0] = make_float4(v1[0], v1[1], v1[2], v1[3]);
    vd[1] = make_float4(v1[4], v1[5], v1[6], v1[7]);
  }
  __syncthreads();

  // ---- layer 1: fused no-max single-pass softmax + attnV ----
  if (t < 15) {
    float o[8] = {0.f, 0.f, 0.f, 0.f, 0.f, 0.f, 0.f, 0.f};
    float sum0 = 0.f, sum1 = 0.f;
#pragma unroll
    for (int u = 0; u < 15; ++u) {
      const float4 k0 = *(const float4*)(kb[e][u]);
      const float4 k1v = *(const float4*)(kb[e][u] + 4);
      const float4 v0 = *(const float4*)(vb[e][u]);
      const float4 v1 = *(const float4*)(vb[e][u] + 4);
      float s0 = q1[0] * k0.x;
      s0 = fmaf(q1[1], k0.y, s0); s0 = fmaf(q1[2], k0.z, s0); s0 = fmaf(q1[3], k0.w, s0);
      float s1 = q1[4] * k1v.x;
      s1 = fmaf(q1[5], k1v.y, s1); s1 = fmaf(q1[6], k1v.z, s1); s1 = fmaf(q1[7], k1v.w, s1);
      const float e0 = exp2_fast(s0);
      const float e1 = exp2_fast(s1);
      sum0 += e0; sum1 += e1;
      o[0] = fmaf(e0, v0.x, o[0]); o[1] = fmaf(e0, v0.y, o[1]);
      o[2] = fmaf(e0, v0.z, o[2]); o[3] = fmaf(e0, v0.w, o[3]);
      o[4] = fmaf(e1, v1.x, o[4]); o[5] = fmaf(e1, v1.y, o[5]);
      o[6] = fmaf(e1, v1.z, o[6]); o[7] = fmaf(e1, v1.w, o[7]);
    }
    const float r0 = 1.0f / sum0, r1 = 1.0f / sum1;
#pragma unroll
    for (int d = 0; d < 4; ++d) { o[d] *= r0; o[4 + d] *= r1; }
    float xn[8];
#pragma unroll
    for (int c = 0; c < 8; ++c) {
      float acc = bo1[c];
#pragma unroll
      for (int j = 0; j < 8; ++j) acc = fmaf(o[j], Wo1[c * 8 + j], acc);
      xn[c] = x[c] + acc;
    }
#pragma unroll
    for (int c = 0; c < 8; ++c) {
      float acc = bl1[c];
#pragma unroll
      for (int j = 0; j < 8; ++j) acc = fmaf(xn[j], Wl1[c * 8 + j], acc);
      x[c] = xn[c] + fmaxf(acc, 0.0f);
    }
  }
  // lane 15 keeps x == 0 so the butterfly sum below is the sum over 15 tokens.

  // ---- epilogue: mean via 16-lane shfl butterfly, then head ----
  float p[8];
#pragma unroll
  for (int j = 0; j < 8; ++j) p[j] = x[j];
#pragma unroll
  for (int j = 0; j < 8; ++j) p[j] += __shfl_xor(p[j], 1);
#pragma unroll
  for (int j = 0; j < 8; ++j) p[j] += __shfl_xor(p[j], 2);
#pragma unroll
  for (int j = 0; j < 8; ++j) p[j] += __shfl_xor(p[j], 4);
#pragma unroll
  for (int j = 0; j < 8; ++j) p[j] += __shfl_xor(p[j], 8);
  float mean[8];
#pragma unroll
  for (int j = 0; j < 8; ++j) mean[j] = p[j] * (1.0f / 15.0f);

  const int obase = ge * 20;
  {
    float acc = bout[t];
#pragma unroll
    for (int j = 0; j < 8; ++j) acc = fmaf(mean[j], Wout[t * 8 + j], acc);
    out[obase + t] = acc;               // a = 0..15
  }
  if (t < 4) {
    const int a = 16 + t;
    float acc = bout[a];
#pragma unroll
    for (int j = 0; j < 8; ++j) acc = fmaf(mean[j], Wout[a * 8 + j], acc);
    out[obase + a] = acc;               // a = 16..19
  }
}

extern "C" void kernel_launch(void* const* d_in, const int* in_sizes, int n_in,
                              void* d_out, int out_size, void* d_ws, size_t ws_size,
                              hipStream_t stream) {
  const int*   dice_type  = (const int*)d_in[0];
  const int*   dice_star  = (const int*)d_in[1];
  const int*   summon_lvl = (const int*)d_in[2];
  const float* emb_dice   = (const float*)d_in[3];
  const float* emb_star   = (const float*)d_in[4];
  const float* emb_btns   = (const float*)d_in[5];
  const float* Wout       = (const float*)d_in[6];
  const float* bout       = (const float*)d_in[7];
  const float* Wqkv0      = (const float*)d_in[8];
  const float* bqkv0      = (const float*)d_in[9];
  const float* Wo0        = (const float*)d_in[10];
  const float* bo0        = (const float*)d_in[11];
  const float* Wl0        = (const float*)d_in[12];
  const float* bl0        = (const float*)d_in[13];
  const float* Wqkv1      = (const float*)d_in[14];
  const float* bqkv1      = (const float*)d_in[15];
  const float* Wo1        = (const float*)d_in[16];
  const float* bo1        = (const float*)d_in[17];
  const float* Wl1        = (const float*)d_in[18];
  const float* bl1        = (const float*)d_in[19];
  float* out = (float*)d_out;

  dim3 grid(BTOT / EPB), block(256);
  hipLaunchKernelGGL(BetterBot_44169443672375_kernel, grid, block, 0, stream,
                     dice_type, dice_star, summon_lvl,
                     emb_dice, emb_star, emb_btns, Wout, bout,
                     Wqkv0, bqkv0, Wo0, bo0, Wl0, bl0,
                     Wqkv1, bqkv1, Wo1, bo1, Wl1, bl1,
                     out);
}